// Round 9
// baseline (138.533 us; speedup 1.0000x reference)
//
#include <hip/hip_runtime.h>

#define EMB_D 128
#define SLOT_CAP 96      // max stored edges/slot; row degree ~Poisson(32), P(>96)~0
#define FILL_CHUNK 8192
#define FILL_THREADS 256

// ---------- Pass 1: claim needed nodes; build slot map + membership bitmap. ----------
__global__ void claim_kernel(const int* __restrict__ user_idx,
                             const int* __restrict__ item_idx,
                             int* __restrict__ node_map,
                             unsigned* __restrict__ bitmap,
                             int B, int U) {
    int t = blockIdx.x * blockDim.x + threadIdx.x;
    if (t >= 2 * B) return;
    int node = (t < B) ? user_idx[t] : (U + item_idx[t - B]);
    atomicCAS(&node_map[node], 0, t + 1);
    atomicOr(&bitmap[node >> 5], 1u << (node & 31));
}

__device__ __forceinline__ void slow_place_cv(int slot, int c, float v,
        float* __restrict__ comp,
        const float* __restrict__ user_emb, const float* __restrict__ item_emb,
        int U) {
    // ~never (deg > SLOT_CAP): exact fallback, comp pre-zeroed
    const float* src = (c < U) ? (user_emb + (size_t)c * EMB_D)
                               : (item_emb + (size_t)(c - U) * EMB_D);
    float* dst = comp + (size_t)slot * EMB_D;
    for (int i = 0; i < EMB_D; ++i) atomicAdd(dst + i, v * src[i]);
}

// ---------- Pass 2: LDS-bitmap filter + per-slot bucketing. ----------
__global__ void __launch_bounds__(FILL_THREADS)
fill3_kernel(const float* __restrict__ user_emb,
             const float* __restrict__ item_emb,
             const float* __restrict__ vals,
             const int* __restrict__ rows,
             const int* __restrict__ cols,
             const int* __restrict__ node_map,
             const unsigned* __restrict__ bitmap, int nwords,
             int* __restrict__ deg,
             int2* __restrict__ edge_buf,
             float* __restrict__ comp,
             long long nnz, int U) {
    extern __shared__ unsigned lbm[];
    const int tid = threadIdx.x;
    for (int i = tid; i < nwords; i += FILL_THREADS) lbm[i] = bitmap[i];
    __syncthreads();

    const long long base = (long long)blockIdx.x * FILL_CHUNK;
    const int K = FILL_CHUNK / FILL_THREADS;   // 32
    for (int kk = 0; kk < K; kk += 8) {
        int   r8[8]; int c8[8]; float v8[8]; bool ok8[8];
#pragma unroll
        for (int j = 0; j < 8; ++j) {          // 24 independent coalesced loads
            long long e = base + (long long)(kk + j) * FILL_THREADS + tid;
            bool ok = (e < nnz);
            ok8[j] = ok;
            long long ec = ok ? e : (nnz - 1);
            r8[j] = rows[ec];
            c8[j] = cols[ec];
            v8[j] = vals[ec];
        }
        bool need[8];
#pragma unroll
        for (int j = 0; j < 8; ++j)            // LDS membership tests
            need[j] = ok8[j] && ((lbm[r8[j] >> 5] >> (r8[j] & 31)) & 1u);
#pragma unroll
        for (int j = 0; j < 8; ++j) {
            if (need[j]) {                     // ~11.5% of edges
                int slot = node_map[r8[j]] - 1;
                int pos = atomicAdd(&deg[slot], 1);
                if (pos < SLOT_CAP)
                    edge_buf[(size_t)slot * SLOT_CAP + pos] =
                        make_int2(c8[j], __float_as_int(v8[j]));
                else
                    slow_place_cv(slot, c8[j], v8[j], comp, user_emb, item_emb, U);
            }
        }
    }
}

// ---------- Tier-B fill (no-LDS fallback, R8 structure). ----------
__global__ void fill_kernel(const float* __restrict__ user_emb,
                            const float* __restrict__ item_emb,
                            const float* __restrict__ vals,
                            const int* __restrict__ rows,
                            const int* __restrict__ cols,
                            const int* __restrict__ node_map,
                            int* __restrict__ deg,
                            int2* __restrict__ edge_buf,
                            float* __restrict__ comp,
                            int nnz, int U) {
    int e = blockIdx.x * blockDim.x + threadIdx.x;
    if (e >= nnz) return;
    int s = node_map[rows[e]];
    if (s == 0) return;
    int slot = s - 1;
    int c = cols[e];
    float v = vals[e];
    int pos = atomicAdd(&deg[slot], 1);
    if (pos < SLOT_CAP)
        edge_buf[(size_t)slot * SLOT_CAP + pos] = make_int2(c, __float_as_int(v));
    else
        slow_place_cv(slot, c, v, comp, user_emb, item_emb, U);
}

__device__ __forceinline__ void fma4(float4& acc, float v, const float4& val) {
    acc.x = fmaf(v, val.x, acc.x);
    acc.y = fmaf(v, val.y, acc.y);
    acc.z = fmaf(v, val.z, acc.z);
    acc.w = fmaf(v, val.w, acc.w);
}

// ---------- Pass 3: one wave per slot; half-wave-per-row float4 gathers. ----------
__global__ void __launch_bounds__(256)
gather_kernel(const float* __restrict__ user_emb,
              const float* __restrict__ item_emb,
              const int2* __restrict__ edge_buf,
              const int* __restrict__ deg,
              float* __restrict__ comp,
              int nslots, int U) {
    int wid  = (blockIdx.x * blockDim.x + threadIdx.x) >> 6;
    int lane = threadIdx.x & 63;
    if (wid >= nslots) return;
    int d = deg[wid];
    bool ovf = (d > SLOT_CAP);
    int dc = ovf ? SLOT_CAP : d;
    const int2* eb = edge_buf + (size_t)wid * SLOT_CAP;
    const int h = lane >> 5;      // half id: edge parity this lane serves
    const int q = lane & 31;      // sublane: owns dims [4q, 4q+4)

    int2 my_e = eb[lane];         // lane i owns edge i (SLOT_CAP >= 64)
    int  myc  = my_e.x;
    const float* mybase = (myc < U) ? (user_emb + (size_t)myc * EMB_D)
                                    : (item_emb + (size_t)(myc - U) * EMB_D);
    unsigned long long mba = (unsigned long long)mybase;
    int   b_lo = (int)(unsigned)mba;
    int   b_hi = (int)(mba >> 32);
    float myv  = __int_as_float(my_e.y);

    float4 acc0 = {0.f, 0.f, 0.f, 0.f};
    float4 acc1 = {0.f, 0.f, 0.f, 0.f};

    const int n0 = dc < 64 ? dc : 64;
    for (int j = 0; j < n0; j += 16) {
        const float* p[8];
        float vv[8];
#pragma unroll
        for (int k = 0; k < 8; ++k) {           // register-only shfl broadcast
            int jj   = j + 2 * k + h;
            int srcl = (jj < n0) ? jj : 0;      // lane 0 always valid (n0 > 0 here)
            int lo = __shfl(b_lo, srcl);
            int hi = __shfl(b_hi, srcl);
            float vx = __shfl(myv, srcl);
            vv[k] = (jj < n0) ? vx : 0.f;       // mask tail contribution
            p[k]  = (const float*)((((unsigned long long)(unsigned)hi) << 32)
                                   | (unsigned)lo);
        }
        float4 x[8];
#pragma unroll
        for (int k = 0; k < 8; ++k)             // 8 independent 512B-row loads
            x[k] = *(const float4*)(p[k] + q * 4);
        __builtin_amdgcn_sched_barrier(0);      // keep all 8 in flight
#pragma unroll
        for (int k = 0; k < 8; ++k)
            fma4((k & 1) ? acc1 : acc0, vv[k], x[k]);
    }

    float4 r;
    r.x = acc0.x + acc1.x;
    r.y = acc0.y + acc1.y;
    r.z = acc0.z + acc1.z;
    r.w = acc0.w + acc1.w;
    r.x += __shfl_xor(r.x, 32);
    r.y += __shfl_xor(r.y, 32);
    r.z += __shfl_xor(r.z, 32);
    r.w += __shfl_xor(r.w, 32);

    if (h == 0) {
        for (int j = 64; j < dc; ++j) {         // rare tail: deg in (64, SLOT_CAP]
            int2 ed = eb[j];
            int c = ed.x;
            float v = __int_as_float(ed.y);
            const float* src = (c < U) ? (user_emb + (size_t)c * EMB_D)
                                       : (item_emb + (size_t)(c - U) * EMB_D);
            float4 xx = *(const float4*)(src + q * 4);
            fma4(r, v, xx);
        }
        float4* dst = (float4*)(comp + (size_t)wid * EMB_D) + q;
        if (ovf) {  // overflow part already added atomically into comp
            float4 o = *dst;
            r.x += o.x; r.y += o.y; r.z += o.z; r.w += o.w;
        }
        *dst = r;   // includes d==0 -> store zeros
    }
}

// ---------- Pass 4: per-pair fused gather + dot. One wave per output. ----------
__global__ void final_kernel(const float* __restrict__ user_emb,
                             const float* __restrict__ item_emb,
                             const int* __restrict__ user_idx,
                             const int* __restrict__ item_idx,
                             const int* __restrict__ node_map,
                             const float* __restrict__ comp,
                             float* __restrict__ out, int B, int U) {
    int wid  = (blockIdx.x * blockDim.x + threadIdx.x) >> 6;
    int lane = threadIdx.x & 63;
    if (wid >= B) return;
    int un  = user_idx[wid];
    int inn = item_idx[wid];
    int su  = node_map[un] - 1;
    int si  = node_map[U + inn] - 1;
    float2 eu = *(const float2*)(user_emb + (size_t)un * EMB_D + lane * 2);
    float2 ei = *(const float2*)(item_emb + (size_t)inn * EMB_D + lane * 2);
    float2 cu = *(const float2*)(comp + (size_t)su * EMB_D + lane * 2);
    float2 ci = *(const float2*)(comp + (size_t)si * EMB_D + lane * 2);
    float p = (eu.x + cu.x) * (ei.x + ci.x) + (eu.y + cu.y) * (ei.y + ci.y);
#pragma unroll
    for (int off = 32; off; off >>= 1) p += __shfl_down(p, off);
    if (lane == 0) out[wid] = 0.25f * p;
}

// ---------- Tier-C fallback (tiny ws): direct atomic scatter ----------
__global__ void scatter_kernel(const float* __restrict__ user_emb,
                               const float* __restrict__ item_emb,
                               const float* __restrict__ vals,
                               const int* __restrict__ rows,
                               const int* __restrict__ cols,
                               const int* __restrict__ node_map,
                               float* __restrict__ comp,
                               int nnz, int U) {
    int e = blockIdx.x * blockDim.x + threadIdx.x;
    int lane = threadIdx.x & 63;
    int s = 0; int c = 0; float v = 0.f;
    if (e < nnz) {
        int r = rows[e];
        s = node_map[r];
        if (s != 0) { c = cols[e]; v = vals[e]; }
    }
    unsigned long long mask = __ballot(s != 0);
    while (mask) {
        int j = __ffsll((long long)mask) - 1;
        mask &= mask - 1;
        int   cj    = __shfl(c, j);
        float vj    = __shfl(v, j);
        int   slotj = __shfl(s, j) - 1;
        const float* src = (cj < U) ? (user_emb + (size_t)cj * EMB_D)
                                    : (item_emb + (size_t)(cj - U) * EMB_D);
        float2 xx = *(const float2*)(src + lane * 2);
        float* dst = comp + (size_t)slotj * EMB_D + lane * 2;
        atomicAdd(dst,     xx.x * vj);
        atomicAdd(dst + 1, xx.y * vj);
    }
}

extern "C" void kernel_launch(void* const* d_in, const int* in_sizes, int n_in,
                              void* d_out, int out_size, void* d_ws, size_t ws_size,
                              hipStream_t stream) {
    const float* user_emb = (const float*)d_in[0];
    const float* item_emb = (const float*)d_in[1];
    const float* adj_vals = (const float*)d_in[2];
    const int*   adj_rows = (const int*)d_in[3];
    const int*   adj_cols = (const int*)d_in[4];
    const int*   user_idx = (const int*)d_in[5];
    const int*   item_idx = (const int*)d_in[6];
    float* out = (float*)d_out;

    int U   = in_sizes[0] / EMB_D;
    int I   = in_sizes[1] / EMB_D;
    int N   = U + I;
    int nnz = in_sizes[2];
    int B   = in_sizes[5];
    int S   = 2 * B;                       // slot count
    int nwords = (N + 31) / 32;            // bitmap words

    // Workspace: [comp S*D f32][map N i32][deg S i32][bitmap nwords u32][edge_buf]
    size_t comp_bytes = (size_t)S * EMB_D * sizeof(float);
    size_t map_bytes  = ((size_t)N * sizeof(int) + 15) & ~(size_t)15;
    size_t deg_bytes  = (((size_t)S) * sizeof(int) + 15) & ~(size_t)15;
    size_t bm_bytes   = (((size_t)nwords) * sizeof(unsigned) + 15) & ~(size_t)15;
    size_t edge_bytes = (size_t)S * SLOT_CAP * sizeof(int2);
    size_t zero_bytes = comp_bytes + map_bytes + deg_bytes + bm_bytes;
    size_t fixed      = zero_bytes + edge_bytes;

    float*    comp     = (float*)d_ws;
    int*      node_map = (int*)((char*)d_ws + comp_bytes);
    int*      deg      = (int*)((char*)d_ws + comp_bytes + map_bytes);
    unsigned* bitmap   = (unsigned*)((char*)d_ws + comp_bytes + map_bytes + deg_bytes);
    int2*     edge_buf = (int2*)((char*)d_ws + zero_bytes);

    size_t lds_bytes = (size_t)nwords * sizeof(unsigned);

    if (ws_size >= fixed) {
        // comp must be zero before fill (overflow fallback atomics land there).
        hipMemsetAsync(d_ws, 0, zero_bytes, stream);
        claim_kernel<<<(S + 255) / 256, 256, 0, stream>>>(user_idx, item_idx,
                                                          node_map, bitmap, B, U);
        if (lds_bytes <= 64 * 1024) {
            int blocks = (int)(((long long)nnz + FILL_CHUNK - 1) / FILL_CHUNK);
            fill3_kernel<<<blocks, FILL_THREADS, lds_bytes, stream>>>(
                user_emb, item_emb, adj_vals, adj_rows, adj_cols, node_map,
                bitmap, nwords, deg, edge_buf, comp, (long long)nnz, U);
        } else {
            fill_kernel<<<(nnz + 255) / 256, 256, 0, stream>>>(
                user_emb, item_emb, adj_vals, adj_rows, adj_cols, node_map,
                deg, edge_buf, comp, nnz, U);
        }
        gather_kernel<<<(S * 64 + 255) / 256, 256, 0, stream>>>(user_emb, item_emb,
                                                                edge_buf, deg, comp,
                                                                S, U);
    } else {
        hipMemsetAsync(d_ws, 0, comp_bytes + map_bytes, stream);
        claim_kernel<<<(S + 255) / 256, 256, 0, stream>>>(user_idx, item_idx,
                                                          node_map, bitmap, B, U);
        scatter_kernel<<<(nnz + 255) / 256, 256, 0, stream>>>(user_emb, item_emb,
                                                              adj_vals, adj_rows,
                                                              adj_cols, node_map,
                                                              comp, nnz, U);
    }
    final_kernel<<<(B * 64 + 255) / 256, 256, 0, stream>>>(user_emb, item_emb,
                                                           user_idx, item_idx,
                                                           node_map, comp, out,
                                                           B, U);
}

// Round 10
// 137.949 us; speedup vs baseline: 1.0042x; 1.0042x over previous
//
#include <hip/hip_runtime.h>

#define EMB_D 128
#define SLOT_CAP 96      // max stored edges/slot; row degree ~Poisson(32), P(>96)~0
#define FILL_CHUNK 8192
#define FILL_THREADS 256

typedef float f32x4 __attribute__((ext_vector_type(4)));

// ---------- Pass 1: claim needed nodes; build slot map + membership bitmap. ----------
__global__ void claim_kernel(const int* __restrict__ user_idx,
                             const int* __restrict__ item_idx,
                             int* __restrict__ node_map,
                             unsigned* __restrict__ bitmap,
                             int B, int U) {
    int t = blockIdx.x * blockDim.x + threadIdx.x;
    if (t >= 2 * B) return;
    int node = (t < B) ? user_idx[t] : (U + item_idx[t - B]);
    atomicCAS(&node_map[node], 0, t + 1);
    atomicOr(&bitmap[node >> 5], 1u << (node & 31));
}

__device__ __forceinline__ void slow_place_cv(int slot, int c, float v,
        float* __restrict__ comp,
        const float* __restrict__ user_emb, const float* __restrict__ item_emb,
        int U) {
    // ~never (deg > SLOT_CAP): exact fallback, comp pre-zeroed
    const float* src = (c < U) ? (user_emb + (size_t)c * EMB_D)
                               : (item_emb + (size_t)(c - U) * EMB_D);
    float* dst = comp + (size_t)slot * EMB_D;
    for (int i = 0; i < EMB_D; ++i) atomicAdd(dst + i, v * src[i]);
}

// ---------- Pass 2: LDS-bitmap filter + per-slot bucketing. ----------
__global__ void __launch_bounds__(FILL_THREADS)
fill3_kernel(const float* __restrict__ user_emb,
             const float* __restrict__ item_emb,
             const float* __restrict__ vals,
             const int* __restrict__ rows,
             const int* __restrict__ cols,
             const int* __restrict__ node_map,
             const unsigned* __restrict__ bitmap, int nwords,
             int* __restrict__ deg,
             int2* __restrict__ edge_buf,
             float* __restrict__ comp,
             long long nnz, int U) {
    extern __shared__ unsigned lbm[];
    const int tid = threadIdx.x;
    for (int i = tid; i < nwords; i += FILL_THREADS) lbm[i] = bitmap[i];
    __syncthreads();

    const long long base = (long long)blockIdx.x * FILL_CHUNK;
    const int K = FILL_CHUNK / FILL_THREADS;   // 32
    for (int kk = 0; kk < K; kk += 8) {
        int   r8[8]; int c8[8]; float v8[8]; bool ok8[8];
#pragma unroll
        for (int j = 0; j < 8; ++j) {          // 24 independent coalesced loads
            long long e = base + (long long)(kk + j) * FILL_THREADS + tid;
            bool ok = (e < nnz);
            ok8[j] = ok;
            long long ec = ok ? e : (nnz - 1);
            r8[j] = rows[ec];
            c8[j] = cols[ec];
            v8[j] = vals[ec];
        }
        bool need[8];
#pragma unroll
        for (int j = 0; j < 8; ++j)            // LDS membership tests
            need[j] = ok8[j] && ((lbm[r8[j] >> 5] >> (r8[j] & 31)) & 1u);
#pragma unroll
        for (int j = 0; j < 8; ++j) {
            if (need[j]) {                     // ~11.5% of edges
                int slot = node_map[r8[j]] - 1;
                int pos = atomicAdd(&deg[slot], 1);
                if (pos < SLOT_CAP)
                    edge_buf[(size_t)slot * SLOT_CAP + pos] =
                        make_int2(c8[j], __float_as_int(v8[j]));
                else
                    slow_place_cv(slot, c8[j], v8[j], comp, user_emb, item_emb, U);
            }
        }
    }
}

// ---------- Tier-B fill (no-LDS fallback). ----------
__global__ void fill_kernel(const float* __restrict__ user_emb,
                            const float* __restrict__ item_emb,
                            const float* __restrict__ vals,
                            const int* __restrict__ rows,
                            const int* __restrict__ cols,
                            const int* __restrict__ node_map,
                            int* __restrict__ deg,
                            int2* __restrict__ edge_buf,
                            float* __restrict__ comp,
                            int nnz, int U) {
    int e = blockIdx.x * blockDim.x + threadIdx.x;
    if (e >= nnz) return;
    int s = node_map[rows[e]];
    if (s == 0) return;
    int slot = s - 1;
    int c = cols[e];
    float v = vals[e];
    int pos = atomicAdd(&deg[slot], 1);
    if (pos < SLOT_CAP)
        edge_buf[(size_t)slot * SLOT_CAP + pos] = make_int2(c, __float_as_int(v));
    else
        slow_place_cv(slot, c, v, comp, user_emb, item_emb, U);
}

// ---------- Pass 3: one wave per slot; 16 asm loads (32 rows) in flight. ----------
__global__ void __launch_bounds__(256)
gather_kernel(const float* __restrict__ user_emb,
              const float* __restrict__ item_emb,
              const int2* __restrict__ edge_buf,
              const int* __restrict__ deg,
              float* __restrict__ comp,
              int nslots, int U) {
    int wid  = (blockIdx.x * blockDim.x + threadIdx.x) >> 6;
    int lane = threadIdx.x & 63;
    if (wid >= nslots) return;
    int d = deg[wid];
    bool ovf = (d > SLOT_CAP);
    int dc = ovf ? SLOT_CAP : d;
    const int2* eb = edge_buf + (size_t)wid * SLOT_CAP;
    const int h = lane >> 5;      // half id: edge parity this lane serves
    const int q = lane & 31;      // sublane: owns dims [4q, 4q+4)

    int2 my_e = eb[lane];         // lane i owns edge i (SLOT_CAP >= 64)
    int  myc  = my_e.x;
    const float* mybase = (myc < U) ? (user_emb + (size_t)myc * EMB_D)
                                    : (item_emb + (size_t)(myc - U) * EMB_D);
    unsigned long long mba = (unsigned long long)mybase;
    int   b_lo = (int)(unsigned)mba;
    int   b_hi = (int)(mba >> 32);
    float myv  = __int_as_float(my_e.y);

    f32x4 acc0 = {0.f, 0.f, 0.f, 0.f};
    f32x4 acc1 = {0.f, 0.f, 0.f, 0.f};

    const int n0 = dc < 64 ? dc : 64;
    for (int j = 0; j < n0; j += 32) {
        const float* p[16];
        float vv[16];
#pragma unroll
        for (int k = 0; k < 16; ++k) {          // register-only shfl broadcast
            int jj   = j + 2 * k + h;
            int srcl = (jj < n0) ? jj : 0;      // lane 0 always valid (n0 > 0 here)
            int lo = __shfl(b_lo, srcl);
            int hi = __shfl(b_hi, srcl);
            float vx = __shfl(myv, srcl);
            vv[k] = (jj < n0) ? vx : 0.f;       // mask tail contribution
            p[k]  = (const float*)((((unsigned long long)(unsigned)hi) << 32)
                                   | (unsigned)lo);
        }
        f32x4 x0, x1, x2, x3, x4, x5, x6, x7;
        f32x4 x8, x9, x10, x11, x12, x13, x14, x15;
#define LOADX(i) \
        asm volatile("global_load_dwordx4 %0, %1, off" \
                     : "=v"(x##i) : "v"(p[i] + q * 4));
        LOADX(0)  LOADX(1)  LOADX(2)  LOADX(3)
        LOADX(4)  LOADX(5)  LOADX(6)  LOADX(7)
        LOADX(8)  LOADX(9)  LOADX(10) LOADX(11)
        LOADX(12) LOADX(13) LOADX(14) LOADX(15)
#undef LOADX
        asm volatile("s_waitcnt vmcnt(0)" ::: "memory");
        __builtin_amdgcn_sched_barrier(0);      // don't hoist FMAs above the wait
#define FMAX(i) { f32x4& A = ((i) & 1) ? acc1 : acc0;                         \
                  A[0] = fmaf(vv[i], x##i[0], A[0]);                          \
                  A[1] = fmaf(vv[i], x##i[1], A[1]);                          \
                  A[2] = fmaf(vv[i], x##i[2], A[2]);                          \
                  A[3] = fmaf(vv[i], x##i[3], A[3]); }
        FMAX(0)  FMAX(1)  FMAX(2)  FMAX(3)
        FMAX(4)  FMAX(5)  FMAX(6)  FMAX(7)
        FMAX(8)  FMAX(9)  FMAX(10) FMAX(11)
        FMAX(12) FMAX(13) FMAX(14) FMAX(15)
#undef FMAX
    }

    f32x4 r;
    r[0] = acc0[0] + acc1[0];
    r[1] = acc0[1] + acc1[1];
    r[2] = acc0[2] + acc1[2];
    r[3] = acc0[3] + acc1[3];
    // combine the two halves: each half held edges of its parity
    r[0] += __shfl_xor(r[0], 32);
    r[1] += __shfl_xor(r[1], 32);
    r[2] += __shfl_xor(r[2], 32);
    r[3] += __shfl_xor(r[3], 32);

    if (h == 0) {
        for (int j = 64; j < dc; ++j) {         // rare tail: deg in (64, SLOT_CAP]
            int2 ed = eb[j];
            int c = ed.x;
            float v = __int_as_float(ed.y);
            const float* src = (c < U) ? (user_emb + (size_t)c * EMB_D)
                                       : (item_emb + (size_t)(c - U) * EMB_D);
            const f32x4 xx = *(const f32x4*)(src + q * 4);
            r[0] = fmaf(v, xx[0], r[0]);
            r[1] = fmaf(v, xx[1], r[1]);
            r[2] = fmaf(v, xx[2], r[2]);
            r[3] = fmaf(v, xx[3], r[3]);
        }
        f32x4* dst = (f32x4*)(comp + (size_t)wid * EMB_D) + q;
        if (ovf) {  // overflow part already added atomically into comp
            f32x4 o = *dst;
            r[0] += o[0]; r[1] += o[1]; r[2] += o[2]; r[3] += o[3];
        }
        *dst = r;   // includes d==0 -> store zeros
    }
}

// ---------- Pass 4: per-pair fused gather + dot. One wave per output. ----------
__global__ void final_kernel(const float* __restrict__ user_emb,
                             const float* __restrict__ item_emb,
                             const int* __restrict__ user_idx,
                             const int* __restrict__ item_idx,
                             const int* __restrict__ node_map,
                             const float* __restrict__ comp,
                             float* __restrict__ out, int B, int U) {
    int wid  = (blockIdx.x * blockDim.x + threadIdx.x) >> 6;
    int lane = threadIdx.x & 63;
    if (wid >= B) return;
    int un  = user_idx[wid];
    int inn = item_idx[wid];
    int su  = node_map[un] - 1;
    int si  = node_map[U + inn] - 1;
    float2 eu = *(const float2*)(user_emb + (size_t)un * EMB_D + lane * 2);
    float2 ei = *(const float2*)(item_emb + (size_t)inn * EMB_D + lane * 2);
    float2 cu = *(const float2*)(comp + (size_t)su * EMB_D + lane * 2);
    float2 ci = *(const float2*)(comp + (size_t)si * EMB_D + lane * 2);
    float p = (eu.x + cu.x) * (ei.x + ci.x) + (eu.y + cu.y) * (ei.y + ci.y);
#pragma unroll
    for (int off = 32; off; off >>= 1) p += __shfl_down(p, off);
    if (lane == 0) out[wid] = 0.25f * p;
}

// ---------- Tier-C fallback (tiny ws): direct atomic scatter ----------
__global__ void scatter_kernel(const float* __restrict__ user_emb,
                               const float* __restrict__ item_emb,
                               const float* __restrict__ vals,
                               const int* __restrict__ rows,
                               const int* __restrict__ cols,
                               const int* __restrict__ node_map,
                               float* __restrict__ comp,
                               int nnz, int U) {
    int e = blockIdx.x * blockDim.x + threadIdx.x;
    int lane = threadIdx.x & 63;
    int s = 0; int c = 0; float v = 0.f;
    if (e < nnz) {
        int r = rows[e];
        s = node_map[r];
        if (s != 0) { c = cols[e]; v = vals[e]; }
    }
    unsigned long long mask = __ballot(s != 0);
    while (mask) {
        int j = __ffsll((long long)mask) - 1;
        mask &= mask - 1;
        int   cj    = __shfl(c, j);
        float vj    = __shfl(v, j);
        int   slotj = __shfl(s, j) - 1;
        const float* src = (cj < U) ? (user_emb + (size_t)cj * EMB_D)
                                    : (item_emb + (size_t)(cj - U) * EMB_D);
        float2 xx = *(const float2*)(src + lane * 2);
        float* dst = comp + (size_t)slotj * EMB_D + lane * 2;
        atomicAdd(dst,     xx.x * vj);
        atomicAdd(dst + 1, xx.y * vj);
    }
}

extern "C" void kernel_launch(void* const* d_in, const int* in_sizes, int n_in,
                              void* d_out, int out_size, void* d_ws, size_t ws_size,
                              hipStream_t stream) {
    const float* user_emb = (const float*)d_in[0];
    const float* item_emb = (const float*)d_in[1];
    const float* adj_vals = (const float*)d_in[2];
    const int*   adj_rows = (const int*)d_in[3];
    const int*   adj_cols = (const int*)d_in[4];
    const int*   user_idx = (const int*)d_in[5];
    const int*   item_idx = (const int*)d_in[6];
    float* out = (float*)d_out;

    int U   = in_sizes[0] / EMB_D;
    int I   = in_sizes[1] / EMB_D;
    int N   = U + I;
    int nnz = in_sizes[2];
    int B   = in_sizes[5];
    int S   = 2 * B;                       // slot count
    int nwords = (N + 31) / 32;            // bitmap words

    // Workspace: [comp S*D f32][map N i32][deg S i32][bitmap nwords u32][edge_buf]
    size_t comp_bytes = (size_t)S * EMB_D * sizeof(float);
    size_t map_bytes  = ((size_t)N * sizeof(int) + 15) & ~(size_t)15;
    size_t deg_bytes  = (((size_t)S) * sizeof(int) + 15) & ~(size_t)15;
    size_t bm_bytes   = (((size_t)nwords) * sizeof(unsigned) + 15) & ~(size_t)15;
    size_t edge_bytes = (size_t)S * SLOT_CAP * sizeof(int2);
    size_t zero_bytes = comp_bytes + map_bytes + deg_bytes + bm_bytes;
    size_t fixed      = zero_bytes + edge_bytes;

    float*    comp     = (float*)d_ws;
    int*      node_map = (int*)((char*)d_ws + comp_bytes);
    int*      deg      = (int*)((char*)d_ws + comp_bytes + map_bytes);
    unsigned* bitmap   = (unsigned*)((char*)d_ws + comp_bytes + map_bytes + deg_bytes);
    int2*     edge_buf = (int2*)((char*)d_ws + zero_bytes);

    size_t lds_bytes = (size_t)nwords * sizeof(unsigned);

    if (ws_size >= fixed) {
        // comp must be zero before fill (overflow fallback atomics land there).
        hipMemsetAsync(d_ws, 0, zero_bytes, stream);
        claim_kernel<<<(S + 255) / 256, 256, 0, stream>>>(user_idx, item_idx,
                                                          node_map, bitmap, B, U);
        if (lds_bytes <= 64 * 1024) {
            int blocks = (int)(((long long)nnz + FILL_CHUNK - 1) / FILL_CHUNK);
            fill3_kernel<<<blocks, FILL_THREADS, lds_bytes, stream>>>(
                user_emb, item_emb, adj_vals, adj_rows, adj_cols, node_map,
                bitmap, nwords, deg, edge_buf, comp, (long long)nnz, U);
        } else {
            fill_kernel<<<(nnz + 255) / 256, 256, 0, stream>>>(
                user_emb, item_emb, adj_vals, adj_rows, adj_cols, node_map,
                deg, edge_buf, comp, nnz, U);
        }
        gather_kernel<<<(S * 64 + 255) / 256, 256, 0, stream>>>(user_emb, item_emb,
                                                                edge_buf, deg, comp,
                                                                S, U);
    } else {
        hipMemsetAsync(d_ws, 0, comp_bytes + map_bytes, stream);
        claim_kernel<<<(S + 255) / 256, 256, 0, stream>>>(user_idx, item_idx,
                                                          node_map, bitmap, B, U);
        scatter_kernel<<<(nnz + 255) / 256, 256, 0, stream>>>(user_emb, item_emb,
                                                              adj_vals, adj_rows,
                                                              adj_cols, node_map,
                                                              comp, nnz, U);
    }
    final_kernel<<<(B * 64 + 255) / 256, 256, 0, stream>>>(user_emb, item_emb,
                                                           user_idx, item_idx,
                                                           node_map, comp, out,
                                                           B, U);
}